// Round 6
// baseline (389.860 us; speedup 1.0000x reference)
//
#include <hip/hip_runtime.h>

typedef __attribute__((ext_vector_type(4))) float floatx4;
typedef __attribute__((ext_vector_type(8))) _Float16 half8;
typedef __attribute__((ext_vector_type(4))) _Float16 half4;

#define TT 2048
#define HIDDEN 2048
#define NH 32
#define NKV 8
#define HD 128
#define QSIZE 4096
#define KVSIZE 1024
#define QKVN 6144
#define QKVNP 6272   // padded: +32 gate cols +96 zero
#define VOFF 5120
#define GOFF 6144
#define WINDOW 512

// ---------------- unified prep: w_qkv^T, w_o^T (64x64 tiles), cvt, pad-zero ----
__global__ __launch_bounds__(256) void prep_kernel(
    const float* __restrict__ w_qkv, const float* __restrict__ w_o,
    const float* __restrict__ hidden, _Float16* __restrict__ Wqkvt,
    _Float16* __restrict__ Wot, _Float16* __restrict__ Xb) {
  __shared__ float tile[64][68];
  int bid = blockIdx.x;
  int tid = threadIdx.x;
  if (bid >= 5120) {
    if (bid < 7168) {
      int i = ((bid - 5120) * 256 + tid) * 8;
      float4 a = *(const float4*)&hidden[i];
      float4 b = *(const float4*)&hidden[i + 4];
      alignas(16) _Float16 o[8] = {(_Float16)a.x, (_Float16)a.y, (_Float16)a.z, (_Float16)a.w,
                                   (_Float16)b.x, (_Float16)b.y, (_Float16)b.z, (_Float16)b.w};
      *(uint4*)&Xb[i] = *(const uint4*)o;
    } else {
      int i = ((bid - 7168) * 256 + tid) * 8;
      *(uint4*)&Wqkvt[(size_t)(GOFF + NH) * HIDDEN + i] = (uint4){0, 0, 0, 0};
    }
    return;
  }
  const float* in;
  _Float16* out;
  int R, C, tilesX, t;
  if (bid < 3072) { in = w_qkv; out = Wqkvt; R = HIDDEN; C = QKVN; tilesX = 96; t = bid; }
  else           { in = w_o;   out = Wot;   R = QSIZE;  C = HIDDEN; tilesX = 32; t = bid - 3072; }
  int bc = (t % tilesX) * 64, br = (t / tilesX) * 64;
  int rr = tid >> 4, l16 = tid & 15;
#pragma unroll
  for (int it = 0; it < 4; ++it) {
    int r = rr + it * 16;
    *(float4*)&tile[r][l16 * 4] = *(const float4*)&in[(size_t)(br + r) * C + bc + l16 * 4];
  }
  __syncthreads();
  int orow = tid >> 2, rr0 = (tid & 3) * 16;
  alignas(16) _Float16 tmp[16];
#pragma unroll
  for (int jj = 0; jj < 16; ++jj) tmp[jj] = (_Float16)tile[rr0 + jj][orow];
  *(uint4*)&out[(size_t)(bc + orow) * R + br + rr0] = *(const uint4*)&tmp[0];
  *(uint4*)&out[(size_t)(bc + orow) * R + br + rr0 + 8] = *(const uint4*)&tmp[8];
}

// ---------------- fp32 [R][C] -> fp16 [C][R] transpose (small, for w_g) --------
__global__ __launch_bounds__(256) void transpose_f32_f16_kernel(
    const float* __restrict__ in, _Float16* __restrict__ out, int R, int C) {
  __shared__ float tile[32][33];
  int bc = blockIdx.x * 32;
  int br = blockIdx.y * 32;
  int c = threadIdx.x & 31;
  int r0 = threadIdx.x >> 5;
#pragma unroll
  for (int i = 0; i < 4; ++i) {
    int r = r0 + 8 * i;
    tile[r][c] = in[(size_t)(br + r) * C + bc + c];
  }
  __syncthreads();
#pragma unroll
  for (int i = 0; i < 4; ++i) {
    int r = r0 + 8 * i;
    out[(size_t)(bc + r) * R + br + c] = (_Float16)tile[c][r];
  }
}

// ---------------- K/V -> fragment-linear repack (z=0: K, z=1: V) -------------
__global__ __launch_bounds__(256) void repack_kv_kernel(const _Float16* __restrict__ Kh,
                                                        const _Float16* __restrict__ QKVh,
                                                        _Float16* __restrict__ Kf,
                                                        _Float16* __restrict__ Vf) {
  __shared__ _Float16 tile[64][136];
  int st = blockIdx.x, kh = blockIdx.y;
  int s0 = st * 64;
  if (blockIdx.z == 0) {
    _Float16* dst = Kf + (size_t)(kh * 32 + st) * 8192;
#pragma unroll
    for (int i = 0; i < 4; ++i) {
      int c = threadIdx.x + i * 256;  // c = jt*256 + kc*64 + quad*16 + n16
      int jt = c >> 8, kc = (c >> 6) & 3, quad = (c >> 4) & 3, n16 = c & 15;
      uint4 v = *(const uint4*)&Kh[((size_t)(s0 + jt * 16 + n16) * NKV + kh) * HD +
                                   kc * 32 + quad * 8];
      *(uint4*)&dst[c * 8] = v;
    }
  } else {
#pragma unroll
    for (int i = 0; i < 4; ++i) {
      int c = threadIdx.x + i * 256;  // c = row*16 + part
      int row = c >> 4, part = c & 15;
      *(uint4*)&tile[row][part * 8] =
          *(const uint4*)&QKVh[(size_t)(s0 + row) * QKVNP + VOFF + kh * HD + part * 8];
    }
    __syncthreads();
    _Float16* dst = Vf + (size_t)(kh * 32 + st) * 8192;
#pragma unroll
    for (int i = 0; i < 4; ++i) {
      int c = threadIdx.x + i * 256;  // c = jd*128 + kc*64 + quad*16 + n16
      int jd = c >> 7, kc = (c >> 6) & 1, quad = (c >> 4) & 3, n16 = c & 15;
      int d = jd * 16 + n16, sb = kc * 32 + quad * 8;
      alignas(16) _Float16 tmp[8];
#pragma unroll
      for (int j = 0; j < 8; ++j) tmp[j] = tile[sb + j][d];
      *(uint4*)&dst[c * 8] = *(const uint4*)tmp;
    }
  }
}

// ---------------- async 16B global->LDS (wave-uniform LDS base + lane*16) -------
__device__ __forceinline__ void async16(const _Float16* g, _Float16* l) {
  __builtin_amdgcn_global_load_lds((const __attribute__((address_space(1))) void*)g,
                                   (__attribute__((address_space(3))) void*)l, 16, 0, 0);
}

// band swizzle: 8 m-tiles x all-n bands for B-tile temporal sharing.
__device__ __forceinline__ void swizzle_mn(int& m0, int& n0) {
  int ntiles = gridDim.y;
  int pid = blockIdx.x + blockIdx.y * gridDim.x;
  int band = pid / (8 * ntiles);
  int wi = pid - band * (8 * ntiles);
  m0 = (band * 8 + (wi & 7)) * 128;
  n0 = (wi >> 3) * 128;
}

// ---------------- MFMA GEMM, BK=64: C[M][N] = A[M][K] * Bt[N][K]^T ------------
// 32 MFMA per barrier-drain (vs 16 at BK=32): halves the structural stall count.
template <typename OutT>
__global__ __launch_bounds__(256, 2) void gemm_bt_kernel(
    const _Float16* __restrict__ A, const _Float16* __restrict__ Bt,
    OutT* __restrict__ C, int M, int N, int K) {
  __shared__ _Float16 As[128 * 64];
  __shared__ _Float16 Bs[128 * 64];
  int tid = threadIdx.x;
  int wave = tid >> 6, lane = tid & 63;
  int wm = wave >> 1, wn = wave & 1;
  int m0, n0;
  swizzle_mn(m0, n0);
  int lr = lane & 15;
  int kq = (lane >> 4) * 8;
  floatx4 acc[4][4];
#pragma unroll
  for (int i = 0; i < 4; ++i)
#pragma unroll
    for (int j = 0; j < 4; ++j) acc[i][j] = (floatx4){0.f, 0.f, 0.f, 0.f};

  for (int k0 = 0; k0 < K; k0 += 64) {
    __syncthreads();
#pragma unroll
    for (int it = 0; it < 4; ++it) {
      int c = tid + it * 256;            // 1024 chunks of 8 halfs per 128x64 tile
      int row = c >> 3, kp = (c & 7) * 8;
      _Float16* la = &As[it * 2048 + wave * 512];
      _Float16* lb = &Bs[it * 2048 + wave * 512];
      async16(&A[(size_t)(m0 + row) * K + k0 + kp], la);
      async16(&Bt[(size_t)(n0 + row) * K + k0 + kp], lb);
    }
    __syncthreads();
#pragma unroll
    for (int kc = 0; kc < 2; ++kc) {
      half8 a[4], b[4];
#pragma unroll
      for (int i = 0; i < 4; ++i)
        a[i] = *(const half8*)&As[(wm * 64 + i * 16 + lr) * 64 + kc * 32 + kq];
#pragma unroll
      for (int j = 0; j < 4; ++j)
        b[j] = *(const half8*)&Bs[(wn * 64 + j * 16 + lr) * 64 + kc * 32 + kq];
#pragma unroll
      for (int i = 0; i < 4; ++i)
#pragma unroll
        for (int j = 0; j < 4; ++j)
          acc[i][j] = __builtin_amdgcn_mfma_f32_16x16x32_f16(a[i], b[j], acc[i][j], 0, 0, 0);
    }
  }
  int rq = (lane >> 4) * 4;
#pragma unroll
  for (int i = 0; i < 4; ++i)
#pragma unroll
    for (int j = 0; j < 4; ++j)
#pragma unroll
      for (int r = 0; r < 4; ++r) {
        int row = m0 + wm * 64 + i * 16 + rq + r;
        int col = n0 + wn * 64 + j * 16 + lr;
        C[(size_t)row * N + col] = (OutT)acc[i][j][r];
      }
}

// ---------------- split-K MFMA GEMM (BK=64), fp32 atomic epilogue -------------
__global__ __launch_bounds__(256, 2) void gemm_bt_splitk_kernel(
    const _Float16* __restrict__ A, const _Float16* __restrict__ Bt,
    float* __restrict__ C, int M, int N, int K, int Ks) {
  __shared__ _Float16 As[128 * 64];
  __shared__ _Float16 Bs[128 * 64];
  int tid = threadIdx.x;
  int wave = tid >> 6, lane = tid & 63;
  int wm = wave >> 1, wn = wave & 1;
  int m0, n0;
  swizzle_mn(m0, n0);
  int kb = blockIdx.z * Ks;
  int lr = lane & 15;
  int kq = (lane >> 4) * 8;
  floatx4 acc[4][4];
#pragma unroll
  for (int i = 0; i < 4; ++i)
#pragma unroll
    for (int j = 0; j < 4; ++j) acc[i][j] = (floatx4){0.f, 0.f, 0.f, 0.f};

  for (int k0 = kb; k0 < kb + Ks; k0 += 64) {
    __syncthreads();
#pragma unroll
    for (int it = 0; it < 4; ++it) {
      int c = tid + it * 256;
      int row = c >> 3, kp = (c & 7) * 8;
      _Float16* la = &As[it * 2048 + wave * 512];
      _Float16* lb = &Bs[it * 2048 + wave * 512];
      async16(&A[(size_t)(m0 + row) * K + k0 + kp], la);
      async16(&Bt[(size_t)(n0 + row) * K + k0 + kp], lb);
    }
    __syncthreads();
#pragma unroll
    for (int kc = 0; kc < 2; ++kc) {
      half8 a[4], b[4];
#pragma unroll
      for (int i = 0; i < 4; ++i)
        a[i] = *(const half8*)&As[(wm * 64 + i * 16 + lr) * 64 + kc * 32 + kq];
#pragma unroll
      for (int j = 0; j < 4; ++j)
        b[j] = *(const half8*)&Bs[(wn * 64 + j * 16 + lr) * 64 + kc * 32 + kq];
#pragma unroll
      for (int i = 0; i < 4; ++i)
#pragma unroll
        for (int j = 0; j < 4; ++j)
          acc[i][j] = __builtin_amdgcn_mfma_f32_16x16x32_f16(a[i], b[j], acc[i][j], 0, 0, 0);
    }
  }
  int rq = (lane >> 4) * 4;
#pragma unroll
  for (int i = 0; i < 4; ++i)
#pragma unroll
    for (int j = 0; j < 4; ++j)
#pragma unroll
      for (int r = 0; r < 4; ++r) {
        int row = m0 + wm * 64 + i * 16 + rq + r;
        int col = n0 + wn * 64 + j * 16 + lr;
        unsafeAtomicAdd(&C[(size_t)row * N + col], acc[i][j][r]);
      }
}

// ---------------- per-head RMSNorm + RoPE (wave per row) ----------------
__global__ __launch_bounds__(256) void normrope_kernel(
    const _Float16* __restrict__ qkv, const float* __restrict__ qw,
    const float* __restrict__ kw, const int* __restrict__ positions,
    _Float16* __restrict__ qh, _Float16* __restrict__ khb) {
  int wid = blockIdx.x * 4 + (threadIdx.x >> 6);
  int lane = threadIdx.x & 63;
  int t, hh;
  const _Float16* src;
  _Float16* dst;
  const float* w;
  if (wid < TT * NH) {
    t = wid >> 5; hh = wid & 31;
    src = qkv + (size_t)t * QKVNP + hh * HD;
    dst = qh + ((size_t)t * NH + hh) * HD;
    w = qw;
  } else {
    int r = wid - TT * NH;
    t = r >> 3; hh = r & 7;
    src = qkv + (size_t)t * QKVNP + QSIZE + hh * HD;
    dst = khb + ((size_t)t * NKV + hh) * HD;
    w = kw;
  }
  float x1 = (float)src[lane];
  float x2 = (float)src[lane + 64];
  float ss = x1 * x1 + x2 * x2;
#pragma unroll
  for (int off = 1; off < 64; off <<= 1) ss += __shfl_xor(ss, off);
  float rr = rsqrtf(ss * (1.0f / 128.0f) + 1e-6f);
  float n1 = x1 * rr * w[lane];
  float n2 = x2 * rr * w[lane + 64];
  float pos = (float)positions[t];
  float invf = exp2f(-(float)lane * (13.287712379549449f / 64.0f));  // 10000^(-lane/64)
  float ang = pos * invf;
  float sn, cs;
  sincosf(ang, &sn, &cs);
  dst[lane] = (_Float16)(n1 * cs - n2 * sn);
  dst[lane + 64] = (_Float16)(n2 * cs + n1 * sn);
}

// ---------------- MFMA sliding-window attention, K-prefetch pipeline ----------
#define PSTR 68
#define M0 8.0f
__global__ __launch_bounds__(256, 2) void attn_kernel(
    const _Float16* __restrict__ Qh, const _Float16* __restrict__ Kf,
    const _Float16* __restrict__ Vf, const _Float16* __restrict__ QKVh,
    _Float16* __restrict__ Og) {
  const float scale = 0.08838834764831845f;  // 128^-0.5
  __shared__ _Float16 Ps[4][2 * 16 * PSTR];
  int tid = threadIdx.x;
  int wave = tid >> 6, lane = tid & 63;
  int n16 = lane & 15, quad = lane >> 4;
  int t0 = blockIdx.x * 32;
  int kh = blockIdx.y;
  int h = kh * 4 + wave;
  _Float16* ps = Ps[wave];

  half8 qf[2][4];
#pragma unroll
  for (int mt = 0; mt < 2; ++mt)
#pragma unroll
    for (int kc = 0; kc < 4; ++kc)
      qf[mt][kc] = *(const half8*)&Qh[((size_t)(t0 + mt * 16 + n16) * NH + h) * HD +
                                      kc * 32 + quad * 8];

  floatx4 O[2][8];
  float lp[2][4];
#pragma unroll
  for (int mt = 0; mt < 2; ++mt) {
#pragma unroll
    for (int jd = 0; jd < 8; ++jd) O[mt][jd] = (floatx4){0.f, 0.f, 0.f, 0.f};
#pragma unroll
    for (int r = 0; r < 4; ++r) lp[mt][r] = 0.f;
  }

  int lo = t0 - (WINDOW - 1);
  if (lo < 0) lo = 0;
  int st0 = lo >> 6;
  int st1 = (t0 + 31) >> 6;

  // preload K frags for first tile
  half8 kfr[4][4];
  {
    const _Float16* kb = Kf + (size_t)(kh * 32 + st0) * 8192;
#pragma unroll
    for (int jt = 0; jt < 4; ++jt)
#pragma unroll
      for (int kc = 0; kc < 4; ++kc)
        kfr[jt][kc] = *(const half8*)&kb[(jt * 4 + kc) * 512 + lane * 8];
  }

  for (int st = st0; st <= st1; ++st) {
    int s0 = st * 64;
    const _Float16* vb = Vf + (size_t)(kh * 32 + st) * 8192;
    // ---- QK^T with current kfr
    floatx4 S[2][4];
#pragma unroll
    for (int mt = 0; mt < 2; ++mt)
#pragma unroll
      for (int jt = 0; jt < 4; ++jt) S[mt][jt] = (floatx4){0.f, 0.f, 0.f, 0.f};
#pragma unroll
    for (int jt = 0; jt < 4; ++jt)
#pragma unroll
      for (int kc = 0; kc < 4; ++kc)
#pragma unroll
        for (int mt = 0; mt < 2; ++mt)
          S[mt][jt] = __builtin_amdgcn_mfma_f32_16x16x32_f16(qf[mt][kc], kfr[jt][kc],
                                                             S[mt][jt], 0, 0, 0);
    // ---- prefetch next tile's K frags (latency covered by softmax+DS+PV)
    if (st < st1) {
      const _Float16* kb = Kf + (size_t)(kh * 32 + st + 1) * 8192;
#pragma unroll
      for (int jt = 0; jt < 4; ++jt)
#pragma unroll
        for (int kc = 0; kc < 4; ++kc)
          kfr[jt][kc] = *(const half8*)&kb[(jt * 4 + kc) * 512 + lane * 8];
    }
    // ---- p = exp(s*scale - M0); masks only on boundary tiles
    bool interior = (t0 >= s0 + 63) && (t0 + 31 - s0 < WINDOW);
    if (interior) {
#pragma unroll
      for (int mt = 0; mt < 2; ++mt)
#pragma unroll
        for (int r = 0; r < 4; ++r) {
          float rs = 0.f;
#pragma unroll
          for (int jt = 0; jt < 4; ++jt) {
            float p = __expf(__builtin_fmaf(S[mt][jt][r], scale, -M0));
            rs += p;
            ps[(mt * 16 + quad * 4 + r) * PSTR + jt * 16 + n16] = (_Float16)p;
          }
          lp[mt][r] += rs;
        }
    } else {
#pragma unroll
      for (int mt = 0; mt < 2; ++mt)
#pragma unroll
        for (int r = 0; r < 4; ++r) {
          int tq = t0 + mt * 16 + quad * 4 + r;
          float rs = 0.f;
#pragma unroll
          for (int jt = 0; jt < 4; ++jt) {
            int diff = tq - (s0 + jt * 16 + n16);
            bool ok = (diff >= 0) && (diff < WINDOW);
            float p = ok ? __expf(__builtin_fmaf(S[mt][jt][r], scale, -M0)) : 0.f;
            rs += p;
            ps[(mt * 16 + quad * 4 + r) * PSTR + jt * 16 + n16] = (_Float16)p;
          }
          lp[mt][r] += rs;
        }
    }
    // ---- P: C-layout -> A-layout via wave-private LDS (in-order DS pipe)
    half8 pf[2][2];
#pragma unroll
    for (int mt = 0; mt < 2; ++mt)
#pragma unroll
      for (int kc = 0; kc < 2; ++kc) {
        half4 lo4 = *(const half4*)&ps[(mt * 16 + n16) * PSTR + kc * 32 + quad * 8];
        half4 hi4 = *(const half4*)&ps[(mt * 16 + n16) * PSTR + kc * 32 + quad * 8 + 4];
        pf[mt][kc] = (half8){lo4[0], lo4[1], lo4[2], lo4[3], hi4[0], hi4[1], hi4[2], hi4[3]};
      }
    // ---- PV
#pragma unroll
    for (int jd = 0; jd < 8; ++jd) {
#pragma unroll
      for (int kc = 0; kc < 2; ++kc) {
        half8 vfr = *(const half8*)&vb[(jd * 2 + kc) * 512 + lane * 8];
#pragma unroll
        for (int mt = 0; mt < 2; ++mt)
          O[mt][jd] = __builtin_amdgcn_mfma_f32_16x16x32_f16(pf[mt][kc], vfr, O[mt][jd], 0, 0, 0);
      }
    }
  }
#pragma unroll
  for (int mt = 0; mt < 2; ++mt)
#pragma unroll
    for (int r = 0; r < 4; ++r) {
      float l = lp[mt][r];
#pragma unroll
      for (int off = 1; off < 16; off <<= 1) l += __shfl_xor(l, off);
      int t = t0 + mt * 16 + quad * 4 + r;
      float gl = (float)QKVh[(size_t)t * QKVNP + GOFF + h];
      float g = (gl > 0.f) ? gl + log1pf(__expf(-gl)) : log1pf(__expf(gl));
      float inv = g / l;
#pragma unroll
      for (int jd = 0; jd < 8; ++jd)
        Og[(size_t)t * QSIZE + h * HD + jd * 16 + n16] = (_Float16)(O[mt][jd][r] * inv);
    }
}

// ---------------- launcher ----------------
extern "C" void kernel_launch(void* const* d_in, const int* in_sizes, int n_in,
                              void* d_out, int out_size, void* d_ws, size_t ws_size,
                              hipStream_t stream) {
  const int* positions = (const int*)d_in[0];
  const float* hidden = (const float*)d_in[1];
  const float* w_qkv = (const float*)d_in[2];
  const float* w_o = (const float*)d_in[3];
  const float* w_g = (const float*)d_in[4];
  const float* q_norm_w = (const float*)d_in[5];
  const float* k_norm_w = (const float*)d_in[6];
  float* out = (float*)d_out;

  char* ws = (char*)d_ws;
  size_t off = 0;
  auto alloc = [&](size_t bytes) {
    void* p = ws + off;
    off += (bytes + 255) & ~(size_t)255;
    return p;
  };
  _Float16* Xb = (_Float16*)alloc((size_t)TT * HIDDEN * 2);
  _Float16* Wqkvt = (_Float16*)alloc((size_t)QKVNP * HIDDEN * 2);
  _Float16* Wot = (_Float16*)alloc((size_t)HIDDEN * QSIZE * 2);
  _Float16* QKVh = (_Float16*)alloc((size_t)TT * QKVNP * 2);
  _Float16* Qh = (_Float16*)alloc((size_t)TT * NH * HD * 2);
  _Float16* Kh = (_Float16*)alloc((size_t)TT * NKV * HD * 2);
  _Float16* Kf = (_Float16*)alloc((size_t)NKV * 32 * 8192 * 2);
  _Float16* Vf = (_Float16*)alloc((size_t)NKV * 32 * 8192 * 2);
  _Float16* Og = (_Float16*)alloc((size_t)TT * QSIZE * 2);

  hipMemsetAsync(d_out, 0, (size_t)out_size * 4, stream);

  prep_kernel<<<7264, 256, 0, stream>>>(w_qkv, w_o, hidden, Wqkvt, Wot, Xb);
  transpose_f32_f16_kernel<<<dim3(1, HIDDEN / 32), 256, 0, stream>>>(
      w_g, Wqkvt + (size_t)GOFF * HIDDEN, HIDDEN, NH);
  gemm_bt_kernel<_Float16><<<dim3(TT / 128, QKVNP / 128), 256, 0, stream>>>(
      Xb, Wqkvt, QKVh, TT, QKVNP, HIDDEN);
  normrope_kernel<<<(TT * (NH + NKV)) / 4, 256, 0, stream>>>(QKVh, q_norm_w, k_norm_w,
                                                             positions, Qh, Kh);
  repack_kv_kernel<<<dim3(32, NKV, 2), 256, 0, stream>>>(Kh, QKVh, Kf, Vf);
  attn_kernel<<<dim3(TT / 32, NKV), 256, 0, stream>>>(Qh, Kf, Vf, QKVh, Og);
  gemm_bt_splitk_kernel<<<dim3(TT / 128, HIDDEN / 128, 2), 256, 0, stream>>>(
      Og, Wot, out, TT, HIDDEN, QSIZE, QSIZE / 2);
}

// Round 7
// 366.701 us; speedup vs baseline: 1.0632x; 1.0632x over previous
//
#include <hip/hip_runtime.h>

typedef __attribute__((ext_vector_type(4))) float floatx4;
typedef __attribute__((ext_vector_type(8))) _Float16 half8;
typedef __attribute__((ext_vector_type(4))) _Float16 half4;

#define TT 2048
#define HIDDEN 2048
#define NH 32
#define NKV 8
#define HD 128
#define QSIZE 4096
#define KVSIZE 1024
#define QKVN 6144
#define QKVNP 6272   // padded: +32 gate cols +96 zero
#define VOFF 5120
#define GOFF 6144
#define WINDOW 512

// ---------------- unified prep: w_qkv^T, w_o^T (64x64 tiles), cvt, pad-zero ----
__global__ __launch_bounds__(256) void prep_kernel(
    const float* __restrict__ w_qkv, const float* __restrict__ w_o,
    const float* __restrict__ hidden, _Float16* __restrict__ Wqkvt,
    _Float16* __restrict__ Wot, _Float16* __restrict__ Xb) {
  __shared__ float tile[64][68];
  int bid = blockIdx.x;
  int tid = threadIdx.x;
  if (bid >= 5120) {
    if (bid < 7168) {
      int i = ((bid - 5120) * 256 + tid) * 8;
      float4 a = *(const float4*)&hidden[i];
      float4 b = *(const float4*)&hidden[i + 4];
      alignas(16) _Float16 o[8] = {(_Float16)a.x, (_Float16)a.y, (_Float16)a.z, (_Float16)a.w,
                                   (_Float16)b.x, (_Float16)b.y, (_Float16)b.z, (_Float16)b.w};
      *(uint4*)&Xb[i] = *(const uint4*)o;
    } else {
      int i = ((bid - 7168) * 256 + tid) * 8;
      *(uint4*)&Wqkvt[(size_t)(GOFF + NH) * HIDDEN + i] = (uint4){0, 0, 0, 0};
    }
    return;
  }
  const float* in;
  _Float16* out;
  int R, C, tilesX, t;
  if (bid < 3072) { in = w_qkv; out = Wqkvt; R = HIDDEN; C = QKVN; tilesX = 96; t = bid; }
  else           { in = w_o;   out = Wot;   R = QSIZE;  C = HIDDEN; tilesX = 32; t = bid - 3072; }
  int bc = (t % tilesX) * 64, br = (t / tilesX) * 64;
  int rr = tid >> 4, l16 = tid & 15;
#pragma unroll
  for (int it = 0; it < 4; ++it) {
    int r = rr + it * 16;
    *(float4*)&tile[r][l16 * 4] = *(const float4*)&in[(size_t)(br + r) * C + bc + l16 * 4];
  }
  __syncthreads();
  int orow = tid >> 2, rr0 = (tid & 3) * 16;
  alignas(16) _Float16 tmp[16];
#pragma unroll
  for (int jj = 0; jj < 16; ++jj) tmp[jj] = (_Float16)tile[rr0 + jj][orow];
  *(uint4*)&out[(size_t)(bc + orow) * R + br + rr0] = *(const uint4*)&tmp[0];
  *(uint4*)&out[(size_t)(bc + orow) * R + br + rr0 + 8] = *(const uint4*)&tmp[8];
}

// ---------------- fp32 [R][C] -> fp16 [C][R] transpose (small, for w_g) --------
__global__ __launch_bounds__(256) void transpose_f32_f16_kernel(
    const float* __restrict__ in, _Float16* __restrict__ out, int R, int C) {
  __shared__ float tile[32][33];
  int bc = blockIdx.x * 32;
  int br = blockIdx.y * 32;
  int c = threadIdx.x & 31;
  int r0 = threadIdx.x >> 5;
#pragma unroll
  for (int i = 0; i < 4; ++i) {
    int r = r0 + 8 * i;
    tile[r][c] = in[(size_t)(br + r) * C + bc + c];
  }
  __syncthreads();
#pragma unroll
  for (int i = 0; i < 4; ++i) {
    int r = r0 + 8 * i;
    out[(size_t)(bc + r) * R + br + c] = (_Float16)tile[c][r];
  }
}

// ---------------- K/V -> fragment-linear repack (z=0: K, z=1: V) -------------
__global__ __launch_bounds__(256) void repack_kv_kernel(const _Float16* __restrict__ Kh,
                                                        const _Float16* __restrict__ QKVh,
                                                        _Float16* __restrict__ Kf,
                                                        _Float16* __restrict__ Vf) {
  __shared__ _Float16 tile[64][136];
  int st = blockIdx.x, kh = blockIdx.y;
  int s0 = st * 64;
  if (blockIdx.z == 0) {
    _Float16* dst = Kf + (size_t)(kh * 32 + st) * 8192;
#pragma unroll
    for (int i = 0; i < 4; ++i) {
      int c = threadIdx.x + i * 256;  // c = jt*256 + kc*64 + quad*16 + n16
      int jt = c >> 8, kc = (c >> 6) & 3, quad = (c >> 4) & 3, n16 = c & 15;
      uint4 v = *(const uint4*)&Kh[((size_t)(s0 + jt * 16 + n16) * NKV + kh) * HD +
                                   kc * 32 + quad * 8];
      *(uint4*)&dst[c * 8] = v;
    }
  } else {
#pragma unroll
    for (int i = 0; i < 4; ++i) {
      int c = threadIdx.x + i * 256;  // c = row*16 + part
      int row = c >> 4, part = c & 15;
      *(uint4*)&tile[row][part * 8] =
          *(const uint4*)&QKVh[(size_t)(s0 + row) * QKVNP + VOFF + kh * HD + part * 8];
    }
    __syncthreads();
    _Float16* dst = Vf + (size_t)(kh * 32 + st) * 8192;
#pragma unroll
    for (int i = 0; i < 4; ++i) {
      int c = threadIdx.x + i * 256;  // c = jd*128 + kc*64 + quad*16 + n16
      int jd = c >> 7, kc = (c >> 6) & 1, quad = (c >> 4) & 3, n16 = c & 15;
      int d = jd * 16 + n16, sb = kc * 32 + quad * 8;
      alignas(16) _Float16 tmp[8];
#pragma unroll
      for (int j = 0; j < 8; ++j) tmp[j] = tile[sb + j][d];
      *(uint4*)&dst[c * 8] = *(const uint4*)tmp;
    }
  }
}

// ---------------- async 16B global->LDS (wave-uniform LDS base + lane*16) -------
__device__ __forceinline__ void async16(const _Float16* g, _Float16* l) {
  __builtin_amdgcn_global_load_lds((const __attribute__((address_space(1))) void*)g,
                                   (__attribute__((address_space(3))) void*)l, 16, 0, 0);
}

// band swizzle: 8 m-tiles x all-n bands for B-tile temporal sharing.
__device__ __forceinline__ void swizzle_mn(int& m0, int& n0) {
  int ntiles = gridDim.y;
  int pid = blockIdx.x + blockIdx.y * gridDim.x;
  int band = pid / (8 * ntiles);
  int wi = pid - band * (8 * ntiles);
  m0 = (band * 8 + (wi & 7)) * 128;
  n0 = (wi >> 3) * 128;
}

// ---------------- MFMA GEMM, BK=64, XOR-swizzled LDS --------------------------
// Row stride 64 halfs (128B = 32 banks) would be 16-way conflicted; storing
// chunk j of row r at slot j^(r&7) spreads reader lanes over all 8 bank groups
// (2 lanes/bank = free). global_load_lds constraint respected: we permute which
// global chunk a lane FETCHES, destination stays base+lane*16.
template <typename OutT>
__global__ __launch_bounds__(256, 2) void gemm_bt_kernel(
    const _Float16* __restrict__ A, const _Float16* __restrict__ Bt,
    OutT* __restrict__ C, int M, int N, int K) {
  __shared__ _Float16 As[128 * 64];
  __shared__ _Float16 Bs[128 * 64];
  int tid = threadIdx.x;
  int wave = tid >> 6, lane = tid & 63;
  int wm = wave >> 1, wn = wave & 1;
  int m0, n0;
  swizzle_mn(m0, n0);
  int lr = lane & 15;
  int quad = lane >> 4;
  floatx4 acc[4][4];
#pragma unroll
  for (int i = 0; i < 4; ++i)
#pragma unroll
    for (int j = 0; j < 4; ++j) acc[i][j] = (floatx4){0.f, 0.f, 0.f, 0.f};

  for (int k0 = 0; k0 < K; k0 += 64) {
    __syncthreads();
#pragma unroll
    for (int it = 0; it < 4; ++it) {
      int c = tid + it * 256;            // 1024 chunks of 8 halfs per 128x64 tile
      int row = c >> 3, j = c & 7;
      int jj = j ^ (row & 7);            // XOR swizzle: fetch permuted chunk
      _Float16* la = &As[it * 2048 + wave * 512];
      _Float16* lb = &Bs[it * 2048 + wave * 512];
      async16(&A[(size_t)(m0 + row) * K + k0 + jj * 8], la);
      async16(&Bt[(size_t)(n0 + row) * K + k0 + jj * 8], lb);
    }
    __syncthreads();
#pragma unroll
    for (int kc = 0; kc < 2; ++kc) {
      int ch = kc * 4 + quad;
      half8 a[4], b[4];
#pragma unroll
      for (int i = 0; i < 4; ++i) {
        int r = wm * 64 + i * 16 + lr;
        a[i] = *(const half8*)&As[r * 64 + (ch ^ (r & 7)) * 8];
      }
#pragma unroll
      for (int j = 0; j < 4; ++j) {
        int r = wn * 64 + j * 16 + lr;
        b[j] = *(const half8*)&Bs[r * 64 + (ch ^ (r & 7)) * 8];
      }
#pragma unroll
      for (int i = 0; i < 4; ++i)
#pragma unroll
        for (int j = 0; j < 4; ++j)
          acc[i][j] = __builtin_amdgcn_mfma_f32_16x16x32_f16(a[i], b[j], acc[i][j], 0, 0, 0);
    }
  }
  int rq = quad * 4;
#pragma unroll
  for (int i = 0; i < 4; ++i)
#pragma unroll
    for (int j = 0; j < 4; ++j)
#pragma unroll
      for (int r = 0; r < 4; ++r) {
        int row = m0 + wm * 64 + i * 16 + rq + r;
        int col = n0 + wn * 64 + j * 16 + lr;
        C[(size_t)row * N + col] = (OutT)acc[i][j][r];
      }
}

// ---------------- split-K MFMA GEMM (BK=64, XOR swizzle), fp32 atomics --------
__global__ __launch_bounds__(256, 2) void gemm_bt_splitk_kernel(
    const _Float16* __restrict__ A, const _Float16* __restrict__ Bt,
    float* __restrict__ C, int M, int N, int K, int Ks) {
  __shared__ _Float16 As[128 * 64];
  __shared__ _Float16 Bs[128 * 64];
  int tid = threadIdx.x;
  int wave = tid >> 6, lane = tid & 63;
  int wm = wave >> 1, wn = wave & 1;
  int m0, n0;
  swizzle_mn(m0, n0);
  int kb = blockIdx.z * Ks;
  int lr = lane & 15;
  int quad = lane >> 4;
  floatx4 acc[4][4];
#pragma unroll
  for (int i = 0; i < 4; ++i)
#pragma unroll
    for (int j = 0; j < 4; ++j) acc[i][j] = (floatx4){0.f, 0.f, 0.f, 0.f};

  for (int k0 = kb; k0 < kb + Ks; k0 += 64) {
    __syncthreads();
#pragma unroll
    for (int it = 0; it < 4; ++it) {
      int c = tid + it * 256;
      int row = c >> 3, j = c & 7;
      int jj = j ^ (row & 7);
      _Float16* la = &As[it * 2048 + wave * 512];
      _Float16* lb = &Bs[it * 2048 + wave * 512];
      async16(&A[(size_t)(m0 + row) * K + k0 + jj * 8], la);
      async16(&Bt[(size_t)(n0 + row) * K + k0 + jj * 8], lb);
    }
    __syncthreads();
#pragma unroll
    for (int kc = 0; kc < 2; ++kc) {
      int ch = kc * 4 + quad;
      half8 a[4], b[4];
#pragma unroll
      for (int i = 0; i < 4; ++i) {
        int r = wm * 64 + i * 16 + lr;
        a[i] = *(const half8*)&As[r * 64 + (ch ^ (r & 7)) * 8];
      }
#pragma unroll
      for (int j = 0; j < 4; ++j) {
        int r = wn * 64 + j * 16 + lr;
        b[j] = *(const half8*)&Bs[r * 64 + (ch ^ (r & 7)) * 8];
      }
#pragma unroll
      for (int i = 0; i < 4; ++i)
#pragma unroll
        for (int j = 0; j < 4; ++j)
          acc[i][j] = __builtin_amdgcn_mfma_f32_16x16x32_f16(a[i], b[j], acc[i][j], 0, 0, 0);
    }
  }
  int rq = quad * 4;
#pragma unroll
  for (int i = 0; i < 4; ++i)
#pragma unroll
    for (int j = 0; j < 4; ++j)
#pragma unroll
      for (int r = 0; r < 4; ++r) {
        int row = m0 + wm * 64 + i * 16 + rq + r;
        int col = n0 + wn * 64 + j * 16 + lr;
        unsafeAtomicAdd(&C[(size_t)row * N + col], acc[i][j][r]);
      }
}

// ---------------- per-head RMSNorm + RoPE (wave per row) ----------------
__global__ __launch_bounds__(256) void normrope_kernel(
    const _Float16* __restrict__ qkv, const float* __restrict__ qw,
    const float* __restrict__ kw, const int* __restrict__ positions,
    _Float16* __restrict__ qh, _Float16* __restrict__ khb) {
  int wid = blockIdx.x * 4 + (threadIdx.x >> 6);
  int lane = threadIdx.x & 63;
  int t, hh;
  const _Float16* src;
  _Float16* dst;
  const float* w;
  if (wid < TT * NH) {
    t = wid >> 5; hh = wid & 31;
    src = qkv + (size_t)t * QKVNP + hh * HD;
    dst = qh + ((size_t)t * NH + hh) * HD;
    w = qw;
  } else {
    int r = wid - TT * NH;
    t = r >> 3; hh = r & 7;
    src = qkv + (size_t)t * QKVNP + QSIZE + hh * HD;
    dst = khb + ((size_t)t * NKV + hh) * HD;
    w = kw;
  }
  float x1 = (float)src[lane];
  float x2 = (float)src[lane + 64];
  float ss = x1 * x1 + x2 * x2;
#pragma unroll
  for (int off = 1; off < 64; off <<= 1) ss += __shfl_xor(ss, off);
  float rr = rsqrtf(ss * (1.0f / 128.0f) + 1e-6f);
  float n1 = x1 * rr * w[lane];
  float n2 = x2 * rr * w[lane + 64];
  float pos = (float)positions[t];
  float invf = exp2f(-(float)lane * (13.287712379549449f / 64.0f));  // 10000^(-lane/64)
  float ang = pos * invf;
  float sn, cs;
  sincosf(ang, &sn, &cs);
  dst[lane] = (_Float16)(n1 * cs - n2 * sn);
  dst[lane + 64] = (_Float16)(n2 * cs + n1 * sn);
}

// ---------------- MFMA sliding-window attention, K-prefetch pipeline ----------
#define PSTR 68
#define M0 8.0f
__global__ __launch_bounds__(256, 2) void attn_kernel(
    const _Float16* __restrict__ Qh, const _Float16* __restrict__ Kf,
    const _Float16* __restrict__ Vf, const _Float16* __restrict__ QKVh,
    _Float16* __restrict__ Og) {
  const float scale = 0.08838834764831845f;  // 128^-0.5
  __shared__ _Float16 Ps[4][2 * 16 * PSTR];
  int tid = threadIdx.x;
  int wave = tid >> 6, lane = tid & 63;
  int n16 = lane & 15, quad = lane >> 4;
  int t0 = blockIdx.x * 32;
  int kh = blockIdx.y;
  int h = kh * 4 + wave;
  _Float16* ps = Ps[wave];

  half8 qf[2][4];
#pragma unroll
  for (int mt = 0; mt < 2; ++mt)
#pragma unroll
    for (int kc = 0; kc < 4; ++kc)
      qf[mt][kc] = *(const half8*)&Qh[((size_t)(t0 + mt * 16 + n16) * NH + h) * HD +
                                      kc * 32 + quad * 8];

  floatx4 O[2][8];
  float lp[2][4];
#pragma unroll
  for (int mt = 0; mt < 2; ++mt) {
#pragma unroll
    for (int jd = 0; jd < 8; ++jd) O[mt][jd] = (floatx4){0.f, 0.f, 0.f, 0.f};
#pragma unroll
    for (int r = 0; r < 4; ++r) lp[mt][r] = 0.f;
  }

  int lo = t0 - (WINDOW - 1);
  if (lo < 0) lo = 0;
  int st0 = lo >> 6;
  int st1 = (t0 + 31) >> 6;

  half8 kfr[4][4];
  {
    const _Float16* kb = Kf + (size_t)(kh * 32 + st0) * 8192;
#pragma unroll
    for (int jt = 0; jt < 4; ++jt)
#pragma unroll
      for (int kc = 0; kc < 4; ++kc)
        kfr[jt][kc] = *(const half8*)&kb[(jt * 4 + kc) * 512 + lane * 8];
  }

  for (int st = st0; st <= st1; ++st) {
    int s0 = st * 64;
    const _Float16* vb = Vf + (size_t)(kh * 32 + st) * 8192;
    floatx4 S[2][4];
#pragma unroll
    for (int mt = 0; mt < 2; ++mt)
#pragma unroll
      for (int jt = 0; jt < 4; ++jt) S[mt][jt] = (floatx4){0.f, 0.f, 0.f, 0.f};
#pragma unroll
    for (int jt = 0; jt < 4; ++jt)
#pragma unroll
      for (int kc = 0; kc < 4; ++kc)
#pragma unroll
        for (int mt = 0; mt < 2; ++mt)
          S[mt][jt] = __builtin_amdgcn_mfma_f32_16x16x32_f16(qf[mt][kc], kfr[jt][kc],
                                                             S[mt][jt], 0, 0, 0);
    if (st < st1) {
      const _Float16* kb = Kf + (size_t)(kh * 32 + st + 1) * 8192;
#pragma unroll
      for (int jt = 0; jt < 4; ++jt)
#pragma unroll
        for (int kc = 0; kc < 4; ++kc)
          kfr[jt][kc] = *(const half8*)&kb[(jt * 4 + kc) * 512 + lane * 8];
    }
    bool interior = (t0 >= s0 + 63) && (t0 + 31 - s0 < WINDOW);
    if (interior) {
#pragma unroll
      for (int mt = 0; mt < 2; ++mt)
#pragma unroll
        for (int r = 0; r < 4; ++r) {
          float rs = 0.f;
#pragma unroll
          for (int jt = 0; jt < 4; ++jt) {
            float p = __expf(__builtin_fmaf(S[mt][jt][r], scale, -M0));
            rs += p;
            ps[(mt * 16 + quad * 4 + r) * PSTR + jt * 16 + n16] = (_Float16)p;
          }
          lp[mt][r] += rs;
        }
    } else {
#pragma unroll
      for (int mt = 0; mt < 2; ++mt)
#pragma unroll
        for (int r = 0; r < 4; ++r) {
          int tq = t0 + mt * 16 + quad * 4 + r;
          float rs = 0.f;
#pragma unroll
          for (int jt = 0; jt < 4; ++jt) {
            int diff = tq - (s0 + jt * 16 + n16);
            bool ok = (diff >= 0) && (diff < WINDOW);
            float p = ok ? __expf(__builtin_fmaf(S[mt][jt][r], scale, -M0)) : 0.f;
            rs += p;
            ps[(mt * 16 + quad * 4 + r) * PSTR + jt * 16 + n16] = (_Float16)p;
          }
          lp[mt][r] += rs;
        }
    }
    half8 pf[2][2];
#pragma unroll
    for (int mt = 0; mt < 2; ++mt)
#pragma unroll
      for (int kc = 0; kc < 2; ++kc) {
        half4 lo4 = *(const half4*)&ps[(mt * 16 + n16) * PSTR + kc * 32 + quad * 8];
        half4 hi4 = *(const half4*)&ps[(mt * 16 + n16) * PSTR + kc * 32 + quad * 8 + 4];
        pf[mt][kc] = (half8){lo4[0], lo4[1], lo4[2], lo4[3], hi4[0], hi4[1], hi4[2], hi4[3]};
      }
#pragma unroll
    for (int jd = 0; jd < 8; ++jd) {
#pragma unroll
      for (int kc = 0; kc < 2; ++kc) {
        half8 vfr = *(const half8*)&vb[(jd * 2 + kc) * 512 + lane * 8];
#pragma unroll
        for (int mt = 0; mt < 2; ++mt)
          O[mt][jd] = __builtin_amdgcn_mfma_f32_16x16x32_f16(pf[mt][kc], vfr, O[mt][jd], 0, 0, 0);
      }
    }
  }
#pragma unroll
  for (int mt = 0; mt < 2; ++mt)
#pragma unroll
    for (int r = 0; r < 4; ++r) {
      float l = lp[mt][r];
#pragma unroll
      for (int off = 1; off < 16; off <<= 1) l += __shfl_xor(l, off);
      int t = t0 + mt * 16 + quad * 4 + r;
      float gl = (float)QKVh[(size_t)t * QKVNP + GOFF + h];
      float g = (gl > 0.f) ? gl + log1pf(__expf(-gl)) : log1pf(__expf(gl));
      float inv = g / l;
#pragma unroll
      for (int jd = 0; jd < 8; ++jd)
        Og[(size_t)t * QSIZE + h * HD + jd * 16 + n16] = (_Float16)(O[mt][jd][r] * inv);
    }
}

// ---------------- launcher ----------------
extern "C" void kernel_launch(void* const* d_in, const int* in_sizes, int n_in,
                              void* d_out, int out_size, void* d_ws, size_t ws_size,
                              hipStream_t stream) {
  const int* positions = (const int*)d_in[0];
  const float* hidden = (const float*)d_in[1];
  const float* w_qkv = (const float*)d_in[2];
  const float* w_o = (const float*)d_in[3];
  const float* w_g = (const float*)d_in[4];
  const float* q_norm_w = (const float*)d_in[5];
  const float* k_norm_w = (const float*)d_in[6];
  float* out = (float*)d_out;

  char* ws = (char*)d_ws;
  size_t off = 0;
  auto alloc = [&](size_t bytes) {
    void* p = ws + off;
    off += (bytes + 255) & ~(size_t)255;
    return p;
  };
  _Float16* Xb = (_Float16*)alloc((size_t)TT * HIDDEN * 2);
  _Float16* Wqkvt = (_Float16*)alloc((size_t)QKVNP * HIDDEN * 2);
  _Float16* Wot = (_Float16*)alloc((size_t)HIDDEN * QSIZE * 2);
  _Float16* QKVh = (_Float16*)alloc((size_t)TT * QKVNP * 2);
  _Float16* Qh = (_Float16*)alloc((size_t)TT * NH * HD * 2);
  _Float16* Kh = (_Float16*)alloc((size_t)TT * NKV * HD * 2);
  _Float16* Kf = (_Float16*)alloc((size_t)NKV * 32 * 8192 * 2);
  _Float16* Vf = (_Float16*)alloc((size_t)NKV * 32 * 8192 * 2);
  _Float16* Og = (_Float16*)alloc((size_t)TT * QSIZE * 2);

  hipMemsetAsync(d_out, 0, (size_t)out_size * 4, stream);

  prep_kernel<<<7264, 256, 0, stream>>>(w_qkv, w_o, hidden, Wqkvt, Wot, Xb);
  transpose_f32_f16_kernel<<<dim3(1, HIDDEN / 32), 256, 0, stream>>>(
      w_g, Wqkvt + (size_t)GOFF * HIDDEN, HIDDEN, NH);
  gemm_bt_kernel<_Float16><<<dim3(TT / 128, QKVNP / 128), 256, 0, stream>>>(
      Xb, Wqkvt, QKVh, TT, QKVNP, HIDDEN);
  normrope_kernel<<<(TT * (NH + NKV)) / 4, 256, 0, stream>>>(QKVh, q_norm_w, k_norm_w,
                                                             positions, Qh, Kh);
  repack_kv_kernel<<<dim3(32, NKV, 2), 256, 0, stream>>>(Kh, QKVh, Kf, Vf);
  attn_kernel<<<dim3(TT / 32, NKV), 256, 0, stream>>>(Qh, Kf, Vf, QKVh, Og);
  gemm_bt_splitk_kernel<<<dim3(TT / 128, HIDDEN / 128, 2), 256, 0, stream>>>(
      Og, Wot, out, TT, HIDDEN, QSIZE, QSIZE / 2);
}

// Round 8
// 351.565 us; speedup vs baseline: 1.1089x; 1.0431x over previous
//
#include <hip/hip_runtime.h>

typedef __attribute__((ext_vector_type(4))) float floatx4;
typedef __attribute__((ext_vector_type(8))) _Float16 half8;
typedef __attribute__((ext_vector_type(4))) _Float16 half4;

#define TT 2048
#define HIDDEN 2048
#define NH 32
#define NKV 8
#define HD 128
#define QSIZE 4096
#define KVSIZE 1024
#define QKVN 6144
#define QKVNP 6272   // padded: +32 gate cols +96 zero
#define VOFF 5120
#define GOFF 6144
#define WINDOW 512

// ---- unified prep: w_qkv^T, w_o^T (64x64 tiles), cvt, pad-zero, w_g^T --------
__global__ __launch_bounds__(256) void prep_kernel(
    const float* __restrict__ w_qkv, const float* __restrict__ w_o,
    const float* __restrict__ hidden, const float* __restrict__ w_g,
    _Float16* __restrict__ Wqkvt, _Float16* __restrict__ Wot,
    _Float16* __restrict__ Xb) {
  __shared__ float tile[64][68];
  int bid = blockIdx.x;
  int tid = threadIdx.x;
  if (bid >= 5120) {
    if (bid < 7168) {
      int i = ((bid - 5120) * 256 + tid) * 8;
      float4 a = *(const float4*)&hidden[i];
      float4 b = *(const float4*)&hidden[i + 4];
      alignas(16) _Float16 o[8] = {(_Float16)a.x, (_Float16)a.y, (_Float16)a.z, (_Float16)a.w,
                                   (_Float16)b.x, (_Float16)b.y, (_Float16)b.z, (_Float16)b.w};
      *(uint4*)&Xb[i] = *(const uint4*)o;
    } else if (bid < 7264) {
      int i = ((bid - 7168) * 256 + tid) * 8;
      *(uint4*)&Wqkvt[(size_t)(GOFF + NH) * HIDDEN + i] = (uint4){0, 0, 0, 0};
    } else {
      // w_g [2048][32] -> Wqkvt rows GOFF..GOFF+31 (32x32 tile per block)
      int br = (bid - 7264) * 32;
      int c = tid & 31, r0 = tid >> 5;
      __shared__ float gt[32][33];
#pragma unroll
      for (int i = 0; i < 4; ++i) {
        int r = r0 + 8 * i;
        gt[r][c] = w_g[(size_t)(br + r) * NH + c];
      }
      __syncthreads();
#pragma unroll
      for (int i = 0; i < 4; ++i) {
        int r = r0 + 8 * i;
        Wqkvt[(size_t)(GOFF + r) * HIDDEN + br + c] = (_Float16)gt[c][r];
      }
    }
    return;
  }
  const float* in;
  _Float16* out;
  int R, C, tilesX, t;
  if (bid < 3072) { in = w_qkv; out = Wqkvt; R = HIDDEN; C = QKVN; tilesX = 96; t = bid; }
  else           { in = w_o;   out = Wot;   R = QSIZE;  C = HIDDEN; tilesX = 32; t = bid - 3072; }
  int bc = (t % tilesX) * 64, br = (t / tilesX) * 64;
  int rr = tid >> 4, l16 = tid & 15;
#pragma unroll
  for (int it = 0; it < 4; ++it) {
    int r = rr + it * 16;
    *(float4*)&tile[r][l16 * 4] = *(const float4*)&in[(size_t)(br + r) * C + bc + l16 * 4];
  }
  __syncthreads();
  int orow = tid >> 2, rr0 = (tid & 3) * 16;
  alignas(16) _Float16 tmp[16];
#pragma unroll
  for (int jj = 0; jj < 16; ++jj) tmp[jj] = (_Float16)tile[rr0 + jj][orow];
  *(uint4*)&out[(size_t)(bc + orow) * R + br + rr0] = *(const uint4*)&tmp[0];
  *(uint4*)&out[(size_t)(bc + orow) * R + br + rr0 + 8] = *(const uint4*)&tmp[8];
}

// ---------------- K/V -> fragment-linear repack (z=0: K, z=1: V) -------------
__global__ __launch_bounds__(256) void repack_kv_kernel(const _Float16* __restrict__ Kh,
                                                        const _Float16* __restrict__ QKVh,
                                                        _Float16* __restrict__ Kf,
                                                        _Float16* __restrict__ Vf) {
  __shared__ _Float16 tile[64][136];
  int st = blockIdx.x, kh = blockIdx.y;
  int s0 = st * 64;
  if (blockIdx.z == 0) {
    _Float16* dst = Kf + (size_t)(kh * 32 + st) * 8192;
#pragma unroll
    for (int i = 0; i < 4; ++i) {
      int c = threadIdx.x + i * 256;  // c = jt*256 + kc*64 + quad*16 + n16
      int jt = c >> 8, kc = (c >> 6) & 3, quad = (c >> 4) & 3, n16 = c & 15;
      uint4 v = *(const uint4*)&Kh[((size_t)(s0 + jt * 16 + n16) * NKV + kh) * HD +
                                   kc * 32 + quad * 8];
      *(uint4*)&dst[c * 8] = v;
    }
  } else {
#pragma unroll
    for (int i = 0; i < 4; ++i) {
      int c = threadIdx.x + i * 256;  // c = row*16 + part
      int row = c >> 4, part = c & 15;
      *(uint4*)&tile[row][part * 8] =
          *(const uint4*)&QKVh[(size_t)(s0 + row) * QKVNP + VOFF + kh * HD + part * 8];
    }
    __syncthreads();
    _Float16* dst = Vf + (size_t)(kh * 32 + st) * 8192;
#pragma unroll
    for (int i = 0; i < 4; ++i) {
      int c = threadIdx.x + i * 256;  // c = jd*128 + kc*64 + quad*16 + n16
      int jd = c >> 7, kc = (c >> 6) & 1, quad = (c >> 4) & 3, n16 = c & 15;
      int d = jd * 16 + n16, sb = kc * 32 + quad * 8;
      alignas(16) _Float16 tmp[8];
#pragma unroll
      for (int j = 0; j < 8; ++j) tmp[j] = tile[sb + j][d];
      *(uint4*)&dst[c * 8] = *(const uint4*)tmp;
    }
  }
}

// ---------------- async 16B global->LDS (wave-uniform LDS base + lane*16) -------
__device__ __forceinline__ void async16(const _Float16* g, _Float16* l) {
  __builtin_amdgcn_global_load_lds((const __attribute__((address_space(1))) void*)g,
                                   (__attribute__((address_space(3))) void*)l, 16, 0, 0);
}

// band swizzle: 8 m-tiles x all-n bands for B-tile temporal sharing.
__device__ __forceinline__ void swizzle_mn(int& m0, int& n0) {
  int ntiles = gridDim.y;
  int pid = blockIdx.x + blockIdx.y * gridDim.x;
  int band = pid / (8 * ntiles);
  int wi = pid - band * (8 * ntiles);
  m0 = (band * 8 + (wi & 7)) * 128;
  n0 = (wi >> 3) * 128;
}

// ---------------- MFMA GEMM, BK=64, XOR-swizzled LDS --------------------------
template <typename OutT>
__global__ __launch_bounds__(256, 2) void gemm_bt_kernel(
    const _Float16* __restrict__ A, const _Float16* __restrict__ Bt,
    OutT* __restrict__ C, int M, int N, int K) {
  __shared__ _Float16 As[128 * 64];
  __shared__ _Float16 Bs[128 * 64];
  int tid = threadIdx.x;
  int wave = tid >> 6, lane = tid & 63;
  int wm = wave >> 1, wn = wave & 1;
  int m0, n0;
  swizzle_mn(m0, n0);
  int lr = lane & 15;
  int quad = lane >> 4;
  floatx4 acc[4][4];
#pragma unroll
  for (int i = 0; i < 4; ++i)
#pragma unroll
    for (int j = 0; j < 4; ++j) acc[i][j] = (floatx4){0.f, 0.f, 0.f, 0.f};

  for (int k0 = 0; k0 < K; k0 += 64) {
    __syncthreads();
#pragma unroll
    for (int it = 0; it < 4; ++it) {
      int c = tid + it * 256;
      int row = c >> 3, j = c & 7;
      int jj = j ^ (row & 7);
      _Float16* la = &As[it * 2048 + wave * 512];
      _Float16* lb = &Bs[it * 2048 + wave * 512];
      async16(&A[(size_t)(m0 + row) * K + k0 + jj * 8], la);
      async16(&Bt[(size_t)(n0 + row) * K + k0 + jj * 8], lb);
    }
    __syncthreads();
#pragma unroll
    for (int kc = 0; kc < 2; ++kc) {
      int ch = kc * 4 + quad;
      half8 a[4], b[4];
#pragma unroll
      for (int i = 0; i < 4; ++i) {
        int r = wm * 64 + i * 16 + lr;
        a[i] = *(const half8*)&As[r * 64 + (ch ^ (r & 7)) * 8];
      }
#pragma unroll
      for (int j = 0; j < 4; ++j) {
        int r = wn * 64 + j * 16 + lr;
        b[j] = *(const half8*)&Bs[r * 64 + (ch ^ (r & 7)) * 8];
      }
#pragma unroll
      for (int i = 0; i < 4; ++i)
#pragma unroll
        for (int j = 0; j < 4; ++j)
          acc[i][j] = __builtin_amdgcn_mfma_f32_16x16x32_f16(a[i], b[j], acc[i][j], 0, 0, 0);
    }
  }
  int rq = quad * 4;
#pragma unroll
  for (int i = 0; i < 4; ++i)
#pragma unroll
    for (int j = 0; j < 4; ++j)
#pragma unroll
      for (int r = 0; r < 4; ++r) {
        int row = m0 + wm * 64 + i * 16 + rq + r;
        int col = n0 + wn * 64 + j * 16 + lr;
        C[(size_t)row * N + col] = (OutT)acc[i][j][r];
      }
}

// ---------------- split-K MFMA GEMM (BK=64, XOR swizzle), fp32 atomics --------
__global__ __launch_bounds__(256, 2) void gemm_bt_splitk_kernel(
    const _Float16* __restrict__ A, const _Float16* __restrict__ Bt,
    float* __restrict__ C, int M, int N, int K, int Ks) {
  __shared__ _Float16 As[128 * 64];
  __shared__ _Float16 Bs[128 * 64];
  int tid = threadIdx.x;
  int wave = tid >> 6, lane = tid & 63;
  int wm = wave >> 1, wn = wave & 1;
  int m0, n0;
  swizzle_mn(m0, n0);
  int kb = blockIdx.z * Ks;
  int lr = lane & 15;
  int quad = lane >> 4;
  floatx4 acc[4][4];
#pragma unroll
  for (int i = 0; i < 4; ++i)
#pragma unroll
    for (int j = 0; j < 4; ++j) acc[i][j] = (floatx4){0.f, 0.f, 0.f, 0.f};

  for (int k0 = kb; k0 < kb + Ks; k0 += 64) {
    __syncthreads();
#pragma unroll
    for (int it = 0; it < 4; ++it) {
      int c = tid + it * 256;
      int row = c >> 3, j = c & 7;
      int jj = j ^ (row & 7);
      _Float16* la = &As[it * 2048 + wave * 512];
      _Float16* lb = &Bs[it * 2048 + wave * 512];
      async16(&A[(size_t)(m0 + row) * K + k0 + jj * 8], la);
      async16(&Bt[(size_t)(n0 + row) * K + k0 + jj * 8], lb);
    }
    __syncthreads();
#pragma unroll
    for (int kc = 0; kc < 2; ++kc) {
      int ch = kc * 4 + quad;
      half8 a[4], b[4];
#pragma unroll
      for (int i = 0; i < 4; ++i) {
        int r = wm * 64 + i * 16 + lr;
        a[i] = *(const half8*)&As[r * 64 + (ch ^ (r & 7)) * 8];
      }
#pragma unroll
      for (int j = 0; j < 4; ++j) {
        int r = wn * 64 + j * 16 + lr;
        b[j] = *(const half8*)&Bs[r * 64 + (ch ^ (r & 7)) * 8];
      }
#pragma unroll
      for (int i = 0; i < 4; ++i)
#pragma unroll
        for (int j = 0; j < 4; ++j)
          acc[i][j] = __builtin_amdgcn_mfma_f32_16x16x32_f16(a[i], b[j], acc[i][j], 0, 0, 0);
    }
  }
  int rq = quad * 4;
#pragma unroll
  for (int i = 0; i < 4; ++i)
#pragma unroll
    for (int j = 0; j < 4; ++j)
#pragma unroll
      for (int r = 0; r < 4; ++r) {
        int row = m0 + wm * 64 + i * 16 + rq + r;
        int col = n0 + wn * 64 + j * 16 + lr;
        unsafeAtomicAdd(&C[(size_t)row * N + col], acc[i][j][r]);
      }
}

// ---------------- per-head RMSNorm + RoPE (wave per row) ----------------
__global__ __launch_bounds__(256) void normrope_kernel(
    const _Float16* __restrict__ qkv, const float* __restrict__ qw,
    const float* __restrict__ kw, const int* __restrict__ positions,
    _Float16* __restrict__ qh, _Float16* __restrict__ khb) {
  int wid = blockIdx.x * 4 + (threadIdx.x >> 6);
  int lane = threadIdx.x & 63;
  int t, hh;
  const _Float16* src;
  _Float16* dst;
  const float* w;
  if (wid < TT * NH) {
    t = wid >> 5; hh = wid & 31;
    src = qkv + (size_t)t * QKVNP + hh * HD;
    dst = qh + ((size_t)t * NH + hh) * HD;
    w = qw;
  } else {
    int r = wid - TT * NH;
    t = r >> 3; hh = r & 7;
    src = qkv + (size_t)t * QKVNP + QSIZE + hh * HD;
    dst = khb + ((size_t)t * NKV + hh) * HD;
    w = kw;
  }
  float x1 = (float)src[lane];
  float x2 = (float)src[lane + 64];
  float ss = x1 * x1 + x2 * x2;
#pragma unroll
  for (int off = 1; off < 64; off <<= 1) ss += __shfl_xor(ss, off);
  float rr = rsqrtf(ss * (1.0f / 128.0f) + 1e-6f);
  float n1 = x1 * rr * w[lane];
  float n2 = x2 * rr * w[lane + 64];
  float pos = (float)positions[t];
  float invf = exp2f(-(float)lane * (13.287712379549449f / 64.0f));  // 10000^(-lane/64)
  float ang = pos * invf;
  float sn, cs;
  sincosf(ang, &sn, &cs);
  dst[lane] = (_Float16)(n1 * cs - n2 * sn);
  dst[lane + 64] = (_Float16)(n2 * cs + n1 * sn);
}

// ---- MFMA sliding-window attention: 16 q-rows/block, 4 blocks/CU residency ---
#define PSTR 68
#define M0 8.0f
__global__ __launch_bounds__(256, 2) void attn_kernel(
    const _Float16* __restrict__ Qh, const _Float16* __restrict__ Kf,
    const _Float16* __restrict__ Vf, const _Float16* __restrict__ QKVh,
    _Float16* __restrict__ Og) {
  const float scale = 0.08838834764831845f;  // 128^-0.5
  __shared__ _Float16 Ps[4][16 * PSTR];
  int tid = threadIdx.x;
  int wave = tid >> 6, lane = tid & 63;
  int n16 = lane & 15, quad = lane >> 4;
  int t0 = blockIdx.x * 16;
  int kh = blockIdx.y;
  int h = kh * 4 + wave;
  _Float16* ps = Ps[wave];

  half8 qf[4];
#pragma unroll
  for (int kc = 0; kc < 4; ++kc)
    qf[kc] = *(const half8*)&Qh[((size_t)(t0 + n16) * NH + h) * HD + kc * 32 + quad * 8];

  floatx4 O[8];
  float lp[4];
#pragma unroll
  for (int jd = 0; jd < 8; ++jd) O[jd] = (floatx4){0.f, 0.f, 0.f, 0.f};
#pragma unroll
  for (int r = 0; r < 4; ++r) lp[r] = 0.f;

  int lo = t0 - (WINDOW - 1);
  if (lo < 0) lo = 0;
  int st0 = lo >> 6;
  int st1 = t0 >> 6;

  half8 kfr[4][4];
  {
    const _Float16* kb = Kf + (size_t)(kh * 32 + st0) * 8192;
#pragma unroll
    for (int jt = 0; jt < 4; ++jt)
#pragma unroll
      for (int kc = 0; kc < 4; ++kc)
        kfr[jt][kc] = *(const half8*)&kb[(jt * 4 + kc) * 512 + lane * 8];
  }

  for (int st = st0; st <= st1; ++st) {
    int s0 = st * 64;
    const _Float16* vb = Vf + (size_t)(kh * 32 + st) * 8192;
    floatx4 S[4];
#pragma unroll
    for (int jt = 0; jt < 4; ++jt) S[jt] = (floatx4){0.f, 0.f, 0.f, 0.f};
#pragma unroll
    for (int jt = 0; jt < 4; ++jt)
#pragma unroll
      for (int kc = 0; kc < 4; ++kc)
        S[jt] = __builtin_amdgcn_mfma_f32_16x16x32_f16(qf[kc], kfr[jt][kc], S[jt], 0, 0, 0);
    if (st < st1) {
      const _Float16* kb = Kf + (size_t)(kh * 32 + st + 1) * 8192;
#pragma unroll
      for (int jt = 0; jt < 4; ++jt)
#pragma unroll
        for (int kc = 0; kc < 4; ++kc)
          kfr[jt][kc] = *(const half8*)&kb[(jt * 4 + kc) * 512 + lane * 8];
    }
    bool interior = (t0 >= s0 + 63) && (t0 + 15 - s0 < WINDOW);
    if (interior) {
#pragma unroll
      for (int r = 0; r < 4; ++r) {
        float rs = 0.f;
#pragma unroll
        for (int jt = 0; jt < 4; ++jt) {
          float p = __expf(__builtin_fmaf(S[jt][r], scale, -M0));
          rs += p;
          ps[(quad * 4 + r) * PSTR + jt * 16 + n16] = (_Float16)p;
        }
        lp[r] += rs;
      }
    } else {
#pragma unroll
      for (int r = 0; r < 4; ++r) {
        int tq = t0 + quad * 4 + r;
        float rs = 0.f;
#pragma unroll
        for (int jt = 0; jt < 4; ++jt) {
          int diff = tq - (s0 + jt * 16 + n16);
          bool ok = (diff >= 0) && (diff < WINDOW);
          float p = ok ? __expf(__builtin_fmaf(S[jt][r], scale, -M0)) : 0.f;
          rs += p;
          ps[(quad * 4 + r) * PSTR + jt * 16 + n16] = (_Float16)p;
        }
        lp[r] += rs;
      }
    }
    half8 pf[2];
#pragma unroll
    for (int kc = 0; kc < 2; ++kc) {
      half4 lo4 = *(const half4*)&ps[n16 * PSTR + kc * 32 + quad * 8];
      half4 hi4 = *(const half4*)&ps[n16 * PSTR + kc * 32 + quad * 8 + 4];
      pf[kc] = (half8){lo4[0], lo4[1], lo4[2], lo4[3], hi4[0], hi4[1], hi4[2], hi4[3]};
    }
#pragma unroll
    for (int jd = 0; jd < 8; ++jd) {
#pragma unroll
      for (int kc = 0; kc < 2; ++kc) {
        half8 vfr = *(const half8*)&vb[(jd * 2 + kc) * 512 + lane * 8];
        O[jd] = __builtin_amdgcn_mfma_f32_16x16x32_f16(pf[kc], vfr, O[jd], 0, 0, 0);
      }
    }
  }
#pragma unroll
  for (int r = 0; r < 4; ++r) {
    float l = lp[r];
#pragma unroll
    for (int off = 1; off < 16; off <<= 1) l += __shfl_xor(l, off);
    int t = t0 + quad * 4 + r;
    float gl = (float)QKVh[(size_t)t * QKVNP + GOFF + h];
    float g = (gl > 0.f) ? gl + log1pf(__expf(-gl)) : log1pf(__expf(gl));
    float inv = g / l;
#pragma unroll
    for (int jd = 0; jd < 8; ++jd)
      Og[(size_t)t * QSIZE + h * HD + jd * 16 + n16] = (_Float16)(O[jd][r] * inv);
  }
}

// ---------------- launcher ----------------
extern "C" void kernel_launch(void* const* d_in, const int* in_sizes, int n_in,
                              void* d_out, int out_size, void* d_ws, size_t ws_size,
                              hipStream_t stream) {
  const int* positions = (const int*)d_in[0];
  const float* hidden = (const float*)d_in[1];
  const float* w_qkv = (const float*)d_in[2];
  const float* w_o = (const float*)d_in[3];
  const float* w_g = (const float*)d_in[4];
  const float* q_norm_w = (const float*)d_in[5];
  const float* k_norm_w = (const float*)d_in[6];
  float* out = (float*)d_out;

  char* ws = (char*)d_ws;
  size_t off = 0;
  auto alloc = [&](size_t bytes) {
    void* p = ws + off;
    off += (bytes + 255) & ~(size_t)255;
    return p;
  };
  _Float16* Xb = (_Float16*)alloc((size_t)TT * HIDDEN * 2);
  _Float16* Wqkvt = (_Float16*)alloc((size_t)QKVNP * HIDDEN * 2);
  _Float16* Wot = (_Float16*)alloc((size_t)HIDDEN * QSIZE * 2);
  _Float16* QKVh = (_Float16*)alloc((size_t)TT * QKVNP * 2);
  _Float16* Qh = (_Float16*)alloc((size_t)TT * NH * HD * 2);
  _Float16* Kh = (_Float16*)alloc((size_t)TT * NKV * HD * 2);
  _Float16* Kf = (_Float16*)alloc((size_t)NKV * 32 * 8192 * 2);
  _Float16* Vf = (_Float16*)alloc((size_t)NKV * 32 * 8192 * 2);
  _Float16* Og = (_Float16*)alloc((size_t)TT * QSIZE * 2);

  hipMemsetAsync(d_out, 0, (size_t)out_size * 4, stream);

  prep_kernel<<<7328, 256, 0, stream>>>(w_qkv, w_o, hidden, w_g, Wqkvt, Wot, Xb);
  gemm_bt_kernel<_Float16><<<dim3(TT / 128, QKVNP / 128), 256, 0, stream>>>(
      Xb, Wqkvt, QKVh, TT, QKVNP, HIDDEN);
  normrope_kernel<<<(TT * (NH + NKV)) / 4, 256, 0, stream>>>(QKVh, q_norm_w, k_norm_w,
                                                             positions, Qh, Kh);
  repack_kv_kernel<<<dim3(32, NKV, 2), 256, 0, stream>>>(Kh, QKVh, Kf, Vf);
  attn_kernel<<<dim3(TT / 16, NKV), 256, 0, stream>>>(Qh, Kf, Vf, QKVh, Og);
  gemm_bt_splitk_kernel<<<dim3(TT / 128, HIDDEN / 128, 4), 256, 0, stream>>>(
      Og, Wot, out, TT, HIDDEN, QSIZE, QSIZE / 4);
}